// Round 16
// baseline (170.683 us; speedup 1.0000x reference)
//
#include <hip/hip_runtime.h>
#include <hip/hip_bf16.h>
#include <type_traits>

#define D 128
#define NBSH 7          // 128 targets per bucket
#define CHUNK 4096      // edges per partition block (196 blocks)
#define CAP 4096        // staging capacity per bucket (mean 2048, sigma~45)
// NOTE: bstage packing (r<<16 | c) requires N < 65536.

typedef _Float16 f16;
typedef f16  f16x8 __attribute__((ext_vector_type(8)));
typedef f16  f16x4 __attribute__((ext_vector_type(4)));
typedef float f32x4 __attribute__((ext_vector_type(4)));

// ------------- dispatch 2: degree count (grid-stride) + W transposes (fused)
__global__ __launch_bounds__(256) void count_transpose(const int* __restrict__ col,
                                                       int* __restrict__ cnt, int E,
                                                       int CB,
                                                       const float* __restrict__ W1,
                                                       const float* __restrict__ W2,
                                                       f16* __restrict__ W1t,
                                                       f16* __restrict__ W2t) {
    const int bid = blockIdx.x;
    if (bid < CB) {
        const int base = bid * 1024;
        const int n = min(1024, E - base);
        for (int i = threadIdx.x; i < n; i += 256)
            atomicAdd(&cnt[col[base + i]], 1);
        return;
    }
    const float* W = (bid == CB) ? W1 : W2;
    f16* Wt = (bid == CB) ? W1t : W2t;
    for (int i = threadIdx.x; i < 16384; i += 256) {
        int n = i >> 7, k = i & 127;
        Wt[i] = (f16)W[k * 128 + n];   // Wt[n][k] = W[k][n]
    }
}

// ----------------------------------------------------- gemm device body (MFMA)
// OPERAND-SWAPPED: A = Wt rows (out-cols), B = X rows.  D: lane holds 4
// CONSECUTIVE out-cols (kg*4+r) of ONE X-row (lane&15) -> f16x4 stores.
// SCALE: multiply X-row by rsqrt(cnt[row]+1) (folds dis[r] into the table).
// Loads guarded (row<N -> zeros); stores unguarded (pad rows = zero row).
template <typename TA, bool SCALE>
__device__ __forceinline__ void gemm_body(const TA* __restrict__ X,
                                          const f16* __restrict__ Wt,
                                          f16* __restrict__ Hh, int N,
                                          const int* __restrict__ cnt, int bid) {
    const int l = threadIdx.x & 63, w = threadIdx.x >> 6;
    const int trow = bid * 64 + w * 16;
    const int xrow = trow + (l & 15);
    const int kg = l >> 4;

    float scale = 1.f;
    if constexpr (SCALE) {
        int cv = (xrow < N) ? cnt[xrow] : 0;
        scale = rsqrtf((float)(cv + 1));
    }

    f16x8 xf[4];
    const TA* xr = X + (size_t)xrow * D;
#pragma unroll
    for (int kt = 0; kt < 4; ++kt) {
        if (xrow < N) {
            if constexpr (std::is_same<TA, float>::value) {
                float4 p0 = *(const float4*)&xr[kt * 32 + kg * 8];
                float4 p1 = *(const float4*)&xr[kt * 32 + kg * 8 + 4];
                xf[kt][0] = (f16)(p0.x * scale); xf[kt][1] = (f16)(p0.y * scale);
                xf[kt][2] = (f16)(p0.z * scale); xf[kt][3] = (f16)(p0.w * scale);
                xf[kt][4] = (f16)(p1.x * scale); xf[kt][5] = (f16)(p1.y * scale);
                xf[kt][6] = (f16)(p1.z * scale); xf[kt][7] = (f16)(p1.w * scale);
            } else {
                xf[kt] = *(const f16x8*)&xr[kt * 32 + kg * 8];
            }
        } else {
#pragma unroll
            for (int j = 0; j < 8; ++j) xf[kt][j] = (f16)0.f;
        }
    }

#pragma unroll
    for (int nt = 0; nt < 8; ++nt) {
        f32x4 acc = {0.f, 0.f, 0.f, 0.f};
        const f16* wrow = Wt + (size_t)(nt * 16 + (l & 15)) * D;
#pragma unroll
        for (int kt = 0; kt < 4; ++kt) {
            f16x8 wf = *(const f16x8*)&wrow[kt * 32 + kg * 8];
            acc = __builtin_amdgcn_mfma_f32_16x16x32_f16(wf, xf[kt], acc, 0, 0, 0);
        }
        f16x4 o;
        o[0] = (f16)acc[0]; o[1] = (f16)acc[1];
        o[2] = (f16)acc[2]; o[3] = (f16)acc[3];
        *(f16x4*)&Hh[(size_t)xrow * D + nt * 16 + kg * 4] = o;
    }
}

// ---------------- fused dispatch: partition (blocks 0..PB-1) + gemm1 (rest)
__global__ __launch_bounds__(256) void gemm1_partition(
    const float* __restrict__ X, const f16* __restrict__ Wt,
    f16* __restrict__ Hh, int N, const int* __restrict__ cnt,
    const int* __restrict__ row, const int* __restrict__ col,
    int* __restrict__ bcur, int* __restrict__ bstage, int E, int NB, int PB) {
    __shared__ char smem[24576];       // sorted 16 KB + 4x512 ints
    const int bid = blockIdx.x;
    if (bid >= PB) {                   // ---- gemm part (dis-scaled)
        gemm_body<float, true>(X, Wt, Hh, N, cnt, bid - PB);
        return;
    }
    // ---- partition part (packed staging: r<<16 | c)
    int* sorted = (int*)smem;                   // 16 KB
    int* hist  = (int*)(smem + 16384);
    int* scanb = hist + 512;
    int* lcur  = scanb + 512;
    int* gdel  = lcur + 512;
    const int t = threadIdx.x;
    const int base = bid * CHUNK;
    const int cnt_e = min(CHUNK, E - base);

    for (int i = t; i < 512; i += 256) hist[i] = 0;
    __syncthreads();
    for (int i = t; i < cnt_e; i += 256)
        atomicAdd(&hist[col[base + i] >> NBSH], 1);
    __syncthreads();
    for (int i = t; i < 512; i += 256) scanb[i] = hist[i];
    __syncthreads();
    for (int s = 1; s < 512; s <<= 1) {
        int i0 = t, i1 = t + 256;
        int v0 = scanb[i0] + ((i0 >= s) ? scanb[i0 - s] : 0);
        int v1 = scanb[i1] + ((i1 >= s) ? scanb[i1 - s] : 0);
        __syncthreads();
        scanb[i0] = v0; scanb[i1] = v1;
        __syncthreads();
    }
    for (int i = t; i < 512; i += 256) lcur[i] = scanb[i] - hist[i];
    __syncthreads();
    for (int i = t; i < cnt_e; i += 256) {
        int r = row[base + i], c = col[base + i];
        int pos = atomicAdd(&lcur[c >> NBSH], 1);
        sorted[pos] = (r << 16) | c;
    }
    __syncthreads();
    for (int b = t; b < NB; b += 256) {
        int k = hist[b];
        if (k > 0) {
            int g = atomicAdd(&bcur[b], k);
            gdel[b] = b * CAP + g - (scanb[b] - k);
        }
    }
    __syncthreads();
    for (int i = t; i < cnt_e; i += 256) {
        int p = sorted[i];
        int b = (p & 0xFFFF) >> NBSH;
        bstage[gdel[b] + i] = p;
    }
}

// --------------- pass 2: per-bucket CSR build (off, dis, eidx) + LDS scatter
__global__ __launch_bounds__(256) void bucket_fill2(const int* __restrict__ bstage,
                                                    const int* __restrict__ bcnt,
                                                    int* __restrict__ off,
                                                    float* __restrict__ dis,
                                                    int* __restrict__ eidx,
                                                    int N, int Etot, int NB) {
    __shared__ int sA[512];
    __shared__ int hist[128];
    __shared__ int lcur[128];
    __shared__ int s_w0;
    __shared__ int leidx[CAP + 128];   // 16.9 KB
    const int t = threadIdx.x;
    const int b = blockIdx.x;
    const int tb = b << NBSH;
    const int ntgt = min(128, N - tb);

    for (int i = t; i < 512; i += 256) sA[i] = (i < NB) ? bcnt[i] : 0;
    __syncthreads();
    for (int s = 1; s < 512; s <<= 1) {
        int i0 = t, i1 = t + 256;
        int v0 = sA[i0] + ((i0 >= s) ? sA[i0 - s] : 0);
        int v1 = sA[i1] + ((i1 >= s) ? sA[i1 - s] : 0);
        __syncthreads();
        sA[i0] = v0; sA[i1] = v1;
        __syncthreads();
    }
    const int cntb = min(bcnt[b], CAP);
    const int gbase = (sA[b] - bcnt[b]) + tb;

    if (t < 128) hist[t] = 0;
    __syncthreads();
    for (int i = t; i < cntb; i += 256)
        atomicAdd(&hist[(bstage[b * CAP + i] & 0xFFFF) - tb], 1);
    __syncthreads();

    int v = 0;
    if (t < 128) v = (t < ntgt) ? hist[t] + 1 : 0;
    int sc = v;
#pragma unroll
    for (int d = 1; d < 64; d <<= 1) {
        int y = __shfl_up(sc, d);
        if ((t & 63) >= d) sc += y;
    }
    if (t == 63) s_w0 = sc;
    __syncthreads();
    int ex = sc - v + ((t >= 64 && t < 128) ? s_w0 : 0);
    if (t < ntgt) {
        off[tb + t] = gbase + ex;
        dis[tb + t] = rsqrtf((float)(hist[t] + 1));
        leidx[ex] = tb + t;            // self-loop first
        lcur[t] = ex + 1;
    }
    if (b == 0 && t == 0) off[N] = Etot;
    __syncthreads();

    for (int i = t; i < cntb; i += 256) {
        int p = bstage[b * CAP + i];
        int pos = atomicAdd(&lcur[(p & 0xFFFF) - tb], 1);
        leidx[pos] = ((unsigned)p) >> 16;
    }
    __syncthreads();
    const int total = cntb + ntgt;
    for (int i = t; i < total; i += 256)
        eidx[gbase + i] = leidx[i];
}

// ------------------------------------------------- standalone gemm (layer 2)
__global__ __launch_bounds__(256) void gemm_mfma_f16(const f16* __restrict__ X,
                                                     const f16* __restrict__ Wt,
                                                     f16* __restrict__ Hh, int N) {
    gemm_body<f16, false>(X, Wt, Hh, N, nullptr, blockIdx.x);
}

// ---------------- SpMM: 1 wave/target, quad-edge f16x8 gathers, NO dis gather
// (table rows pre-scaled by dis[r]).  OOB tail slots -> zero row ZR.
// HEAD=0: store dc*relu(dc*acc+bias) fp16 (scaled for next layer).
// HEAD=1: relu(dc*acc+bias) -> fused 128x3 head.
template <int HEAD>
__global__ __launch_bounds__(256) void spmm_quad(const f16* __restrict__ G,
                                                 const int* __restrict__ off,
                                                 const int* __restrict__ eidx,
                                                 const float* __restrict__ dis,
                                                 const float* __restrict__ bias,
                                                 const float* __restrict__ Wh,
                                                 const float* __restrict__ bh,
                                                 f16* __restrict__ Oh,
                                                 float* __restrict__ out,
                                                 int N, int ZR) {
    const int c = blockIdx.x * 4 + (threadIdx.x >> 6);
    if (c >= N) return;
    const int lane = threadIdx.x & 63;
    const int q = lane >> 4;           // edge slot within quad
    const int f = (lane & 15) * 8;     // feature base (8 feats/lane)
    const int s = off[c], e = off[c + 1];
    const float dc = dis[c];
    float a0 = 0.f, a1 = 0.f, a2 = 0.f, a3 = 0.f;
    float a4 = 0.f, a5 = 0.f, a6 = 0.f, a7 = 0.f;

    int k = s;
    for (; k + 16 <= e; k += 16) {
        int r[4];
#pragma unroll
        for (int j = 0; j < 4; ++j) r[j] = eidx[k + 4 * j + q];
        f16x8 h[4];
#pragma unroll
        for (int j = 0; j < 4; ++j)
            h[j] = *(const f16x8*)&G[(size_t)r[j] * D + f];
#pragma unroll
        for (int j = 0; j < 4; ++j) {
            a0 += (float)h[j][0]; a1 += (float)h[j][1];
            a2 += (float)h[j][2]; a3 += (float)h[j][3];
            a4 += (float)h[j][4]; a5 += (float)h[j][5];
            a6 += (float)h[j][6]; a7 += (float)h[j][7];
        }
    }
    if (k < e) {   // guarded full-depth tail: OOB -> zero row (contributes 0)
        int r[4];
#pragma unroll
        for (int j = 0; j < 4; ++j) {
            int idx = k + 4 * j + q;
            r[j] = (idx < e) ? eidx[idx] : ZR;
        }
        f16x8 h[4];
#pragma unroll
        for (int j = 0; j < 4; ++j)
            h[j] = *(const f16x8*)&G[(size_t)r[j] * D + f];
#pragma unroll
        for (int j = 0; j < 4; ++j) {
            a0 += (float)h[j][0]; a1 += (float)h[j][1];
            a2 += (float)h[j][2]; a3 += (float)h[j][3];
            a4 += (float)h[j][4]; a5 += (float)h[j][5];
            a6 += (float)h[j][6]; a7 += (float)h[j][7];
        }
    }
    // combine across the 4 lane groups (edges mod 4)
#pragma unroll
    for (int sft = 16; sft < 64; sft <<= 1) {
        a0 += __shfl_xor(a0, sft); a1 += __shfl_xor(a1, sft);
        a2 += __shfl_xor(a2, sft); a3 += __shfl_xor(a3, sft);
        a4 += __shfl_xor(a4, sft); a5 += __shfl_xor(a5, sft);
        a6 += __shfl_xor(a6, sft); a7 += __shfl_xor(a7, sft);
    }
    const float4 bv0 = *(const float4*)&bias[f];
    const float4 bv1 = *(const float4*)&bias[f + 4];
    const float r0 = fmaxf(dc * a0 + bv0.x, 0.f), r1 = fmaxf(dc * a1 + bv0.y, 0.f);
    const float r2 = fmaxf(dc * a2 + bv0.z, 0.f), r3 = fmaxf(dc * a3 + bv0.w, 0.f);
    const float r4 = fmaxf(dc * a4 + bv1.x, 0.f), r5 = fmaxf(dc * a5 + bv1.y, 0.f);
    const float r6 = fmaxf(dc * a6 + bv1.z, 0.f), r7 = fmaxf(dc * a7 + bv1.w, 0.f);

    if constexpr (HEAD == 0) {
        if (q == 0) {                  // store dis[c]-prescaled for next layer
            f16x8 o;
            o[0] = (f16)(dc * r0); o[1] = (f16)(dc * r1);
            o[2] = (f16)(dc * r2); o[3] = (f16)(dc * r3);
            o[4] = (f16)(dc * r4); o[5] = (f16)(dc * r5);
            o[6] = (f16)(dc * r6); o[7] = (f16)(dc * r7);
            *(f16x8*)&Oh[(size_t)c * D + f] = o;
        }
    } else {
        const float* whp = Wh + f * 3;
        float p0 = r0 * whp[0]  + r1 * whp[3]  + r2 * whp[6]  + r3 * whp[9]
                 + r4 * whp[12] + r5 * whp[15] + r6 * whp[18] + r7 * whp[21];
        float p1 = r0 * whp[1]  + r1 * whp[4]  + r2 * whp[7]  + r3 * whp[10]
                 + r4 * whp[13] + r5 * whp[16] + r6 * whp[19] + r7 * whp[22];
        float p2 = r0 * whp[2]  + r1 * whp[5]  + r2 * whp[8]  + r3 * whp[11]
                 + r4 * whp[14] + r5 * whp[17] + r6 * whp[20] + r7 * whp[23];
#pragma unroll
        for (int sft = 1; sft < 16; sft <<= 1) {
            p0 += __shfl_xor(p0, sft);
            p1 += __shfl_xor(p1, sft);
            p2 += __shfl_xor(p2, sft);
        }
        if (lane == 0) {
            out[(size_t)c * 3 + 0] = p0 + bh[0];
            out[(size_t)c * 3 + 1] = p1 + bh[1];
            out[(size_t)c * 3 + 2] = p2 + bh[2];
        }
    }
}

// ---------------------------------------------------------------------------
extern "C" void kernel_launch(void* const* d_in, const int* in_sizes, int n_in,
                              void* d_out, int out_size, void* d_ws, size_t ws_size,
                              hipStream_t stream) {
    const float* x  = (const float*)d_in[0];
    const int*   ei = (const int*)d_in[1];
    const float* W1 = (const float*)d_in[2];
    const float* b1 = (const float*)d_in[3];
    const float* W2 = (const float*)d_in[4];
    const float* b2 = (const float*)d_in[5];
    const float* Wh = (const float*)d_in[6];
    const float* bh = (const float*)d_in[7];
    float* out = (float*)d_out;

    const int N = in_sizes[0] / D;       // 50000 (< 65536 for packing)
    const int E = in_sizes[1] / 2;       // 800000
    const int Etot = E + N;
    const int* row = ei;
    const int* col = ei + E;
    const int NB = (N + 127) >> NBSH;    // 391 buckets
    const int PB = (E + CHUNK - 1) / CHUNK;   // 196 partition blocks
    const int CB = (E + 1023) / 1024;    // 782 count blocks
    const int gblocks = (N + 64 + 63) / 64;   // 783: covers rows 0..N (zero row)
    const int ZR = N;                    // zero-row index for OOB tail slots
    const int sblocks = (N + 3) / 4;     // 12500

    // -------- workspace layout
    char* ws = (char*)d_ws;
    size_t o = 0;
    auto alloc = [&](size_t bytes) -> char* {
        char* p = ws + o;
        o = (o + bytes + 255) & ~(size_t)255;
        return p;
    };
    int*   cnt    = (int*)  alloc((size_t)N * 4);      // degree counts
    int*   bcur   = (int*)  alloc((size_t)NB * 4);     // (adjacent to cnt)
    int*   off    = (int*)  alloc((size_t)(N + 1) * 4);
    float* dis    = (float*)alloc((size_t)N * 4);
    int*   bstage = (int*)  alloc((size_t)NB * CAP * 4);   // 6.4 MB packed
    int*   eidx   = (int*)  alloc((size_t)Etot * 4);
    f16*   W1t    = (f16*)  alloc((size_t)128 * 128 * 2);
    f16*   W2t    = (f16*)  alloc((size_t)128 * 128 * 2);
    f16*   Hb0    = (f16*)  alloc((size_t)gblocks * 64 * D * 2);  // ping (+pad)
    f16*   Hb1    = (f16*)  alloc((size_t)gblocks * 64 * D * 2);  // pong (+pad)
    (void)ws_size;

    // zero cnt + bcur in one memset (they are adjacent in the layout)
    size_t zspan = (size_t)((char*)(bcur + NB) - (char*)cnt);
    hipMemsetAsync(cnt, 0, zspan, stream);
    count_transpose<<<CB + 2, 256, 0, stream>>>(col, cnt, E, CB, W1, W2, W1t, W2t);
    gemm1_partition<<<PB + gblocks, 256, 0, stream>>>(x, W1t, Hb0, N, cnt,
                                                      row, col, bcur, bstage,
                                                      E, NB, PB);
    bucket_fill2<<<NB, 256, 0, stream>>>(bstage, bcur, off, dis, eidx, N, Etot, NB);
    spmm_quad<0><<<sblocks, 256, 0, stream>>>(Hb0, off, eidx, dis, b1,
                                              nullptr, nullptr, Hb1, nullptr, N, ZR);
    gemm_mfma_f16<<<gblocks, 256, 0, stream>>>(Hb1, W2t, Hb0, N);
    spmm_quad<1><<<sblocks, 256, 0, stream>>>(Hb0, off, eidx, dis, b2,
                                              Wh, bh, nullptr, out, N, ZR);
}

// Round 17
// 131.862 us; speedup vs baseline: 1.2944x; 1.2944x over previous
//
#include <hip/hip_runtime.h>
#include <hip/hip_bf16.h>
#include <type_traits>

#define D 128
#define NBSH 7          // 128 targets per bucket
#define CHUNK 4096      // edges per partition block (196 blocks)
#define CAP 4096        // staging capacity per bucket (mean 2048, sigma~45)
// NOTE: bstage packing (r<<16 | c) requires N < 65536.

typedef _Float16 f16;
typedef f16  f16x8 __attribute__((ext_vector_type(8)));
typedef f16  f16x4 __attribute__((ext_vector_type(4)));
typedef float f32x4 __attribute__((ext_vector_type(4)));

// --------------------- W transpose + fp16 (one-time); block 2 zeroes bcur
__global__ __launch_bounds__(1024) void transpose_w(const float* __restrict__ W1,
                                                    const float* __restrict__ W2,
                                                    f16* __restrict__ W1t,
                                                    f16* __restrict__ W2t,
                                                    int* __restrict__ bcur, int NB) {
    if (blockIdx.x == 2) {
        for (int i = threadIdx.x; i < NB; i += 1024) bcur[i] = 0;
        return;
    }
    const float* W = blockIdx.x ? W2 : W1;
    f16* Wt = blockIdx.x ? W2t : W1t;
    __shared__ float Wl[128 * 130];
    const int t = threadIdx.x;
    for (int i = t; i < 16384; i += 1024)
        Wl[(i >> 7) * 130 + (i & 127)] = W[i];
    __syncthreads();
    for (int i = t; i < 16384; i += 1024) {
        int n = i >> 7, k = i & 127;
        Wt[i] = (f16)Wl[k * 130 + n];   // Wt[n][k] = W[k][n]
    }
}

// ----------------------------------------------------- gemm device body (MFMA)
// OPERAND-SWAPPED: A = Wt rows (out-cols), B = X rows.  D: lane holds 4
// CONSECUTIVE out-cols (kg*4+r) of ONE X-row (lane&15) -> f16x4 stores.
// Loads guarded (row<N -> zeros); stores unguarded (pad rows = zero row).
template <typename TA>
__device__ __forceinline__ void gemm_body(const TA* __restrict__ X,
                                          const f16* __restrict__ Wt,
                                          f16* __restrict__ Hh, int N, int bid) {
    const int l = threadIdx.x & 63, w = threadIdx.x >> 6;
    const int trow = bid * 64 + w * 16;
    const int xrow = trow + (l & 15);
    const int kg = l >> 4;

    f16x8 xf[4];
    const TA* xr = X + (size_t)xrow * D;
#pragma unroll
    for (int kt = 0; kt < 4; ++kt) {
        if (xrow < N) {
            if constexpr (std::is_same<TA, float>::value) {
                float4 p0 = *(const float4*)&xr[kt * 32 + kg * 8];
                float4 p1 = *(const float4*)&xr[kt * 32 + kg * 8 + 4];
                xf[kt][0] = (f16)p0.x; xf[kt][1] = (f16)p0.y;
                xf[kt][2] = (f16)p0.z; xf[kt][3] = (f16)p0.w;
                xf[kt][4] = (f16)p1.x; xf[kt][5] = (f16)p1.y;
                xf[kt][6] = (f16)p1.z; xf[kt][7] = (f16)p1.w;
            } else {
                xf[kt] = *(const f16x8*)&xr[kt * 32 + kg * 8];
            }
        } else {
#pragma unroll
            for (int j = 0; j < 8; ++j) xf[kt][j] = (f16)0.f;
        }
    }

#pragma unroll
    for (int nt = 0; nt < 8; ++nt) {
        f32x4 acc = {0.f, 0.f, 0.f, 0.f};
        const f16* wrow = Wt + (size_t)(nt * 16 + (l & 15)) * D;
#pragma unroll
        for (int kt = 0; kt < 4; ++kt) {
            f16x8 wf = *(const f16x8*)&wrow[kt * 32 + kg * 8];
            acc = __builtin_amdgcn_mfma_f32_16x16x32_f16(wf, xf[kt], acc, 0, 0, 0);
        }
        f16x4 o;
        o[0] = (f16)acc[0]; o[1] = (f16)acc[1];
        o[2] = (f16)acc[2]; o[3] = (f16)acc[3];
        *(f16x4*)&Hh[(size_t)xrow * D + nt * 16 + kg * 4] = o;
    }
}

// ---------------- fused dispatch: partition (blocks 0..PB-1) + gemm1 (rest)
__global__ __launch_bounds__(256) void gemm1_partition(
    const float* __restrict__ X, const f16* __restrict__ Wt,
    f16* __restrict__ Hh, int N,
    const int* __restrict__ row, const int* __restrict__ col,
    int* __restrict__ bcur, int* __restrict__ bstage, int E, int NB, int PB) {
    __shared__ char smem[24576];       // sorted 16 KB + 4x512 ints
    const int bid = blockIdx.x;
    if (bid >= PB) {                   // ---- gemm part
        gemm_body<float>(X, Wt, Hh, N, bid - PB);
        return;
    }
    // ---- partition part (packed staging: r<<16 | c)
    int* sorted = (int*)smem;                   // 16 KB
    int* hist  = (int*)(smem + 16384);
    int* scanb = hist + 512;
    int* lcur  = scanb + 512;
    int* gdel  = lcur + 512;
    const int t = threadIdx.x;
    const int base = bid * CHUNK;
    const int cnt_e = min(CHUNK, E - base);

    for (int i = t; i < 512; i += 256) hist[i] = 0;
    __syncthreads();
    for (int i = t; i < cnt_e; i += 256)
        atomicAdd(&hist[col[base + i] >> NBSH], 1);
    __syncthreads();
    for (int i = t; i < 512; i += 256) scanb[i] = hist[i];
    __syncthreads();
    for (int s = 1; s < 512; s <<= 1) {
        int i0 = t, i1 = t + 256;
        int v0 = scanb[i0] + ((i0 >= s) ? scanb[i0 - s] : 0);
        int v1 = scanb[i1] + ((i1 >= s) ? scanb[i1 - s] : 0);
        __syncthreads();
        scanb[i0] = v0; scanb[i1] = v1;
        __syncthreads();
    }
    for (int i = t; i < 512; i += 256) lcur[i] = scanb[i] - hist[i];
    __syncthreads();
    for (int i = t; i < cnt_e; i += 256) {
        int r = row[base + i], c = col[base + i];
        int pos = atomicAdd(&lcur[c >> NBSH], 1);
        sorted[pos] = (r << 16) | c;
    }
    __syncthreads();
    for (int b = t; b < NB; b += 256) {
        int k = hist[b];
        if (k > 0) {
            int g = atomicAdd(&bcur[b], k);
            gdel[b] = b * CAP + g - (scanb[b] - k);
        }
    }
    __syncthreads();
    for (int i = t; i < cnt_e; i += 256) {
        int p = sorted[i];
        int b = (p & 0xFFFF) >> NBSH;
        bstage[gdel[b] + i] = p;
    }
}

// --------------- pass 2: per-bucket CSR build (off, dis, eidx) + LDS scatter
__global__ __launch_bounds__(256) void bucket_fill2(const int* __restrict__ bstage,
                                                    const int* __restrict__ bcnt,
                                                    int* __restrict__ off,
                                                    float* __restrict__ dis,
                                                    int* __restrict__ eidx,
                                                    int N, int Etot, int NB) {
    __shared__ int sA[512];
    __shared__ int hist[128];
    __shared__ int lcur[128];
    __shared__ int s_w0;
    __shared__ int leidx[CAP + 128];   // 16.9 KB
    const int t = threadIdx.x;
    const int b = blockIdx.x;
    const int tb = b << NBSH;
    const int ntgt = min(128, N - tb);

    for (int i = t; i < 512; i += 256) sA[i] = (i < NB) ? bcnt[i] : 0;
    __syncthreads();
    for (int s = 1; s < 512; s <<= 1) {
        int i0 = t, i1 = t + 256;
        int v0 = sA[i0] + ((i0 >= s) ? sA[i0 - s] : 0);
        int v1 = sA[i1] + ((i1 >= s) ? sA[i1 - s] : 0);
        __syncthreads();
        sA[i0] = v0; sA[i1] = v1;
        __syncthreads();
    }
    const int cntb = min(bcnt[b], CAP);
    const int gbase = (sA[b] - bcnt[b]) + tb;

    if (t < 128) hist[t] = 0;
    __syncthreads();
    for (int i = t; i < cntb; i += 256)
        atomicAdd(&hist[(bstage[b * CAP + i] & 0xFFFF) - tb], 1);
    __syncthreads();

    int v = 0;
    if (t < 128) v = (t < ntgt) ? hist[t] + 1 : 0;
    int sc = v;
#pragma unroll
    for (int d = 1; d < 64; d <<= 1) {
        int y = __shfl_up(sc, d);
        if ((t & 63) >= d) sc += y;
    }
    if (t == 63) s_w0 = sc;
    __syncthreads();
    int ex = sc - v + ((t >= 64 && t < 128) ? s_w0 : 0);
    if (t < ntgt) {
        off[tb + t] = gbase + ex;
        dis[tb + t] = rsqrtf((float)(hist[t] + 1));
        leidx[ex] = tb + t;            // self-loop first
        lcur[t] = ex + 1;
    }
    if (b == 0 && t == 0) off[N] = Etot;
    __syncthreads();

    for (int i = t; i < cntb; i += 256) {
        int p = bstage[b * CAP + i];
        int pos = atomicAdd(&lcur[(p & 0xFFFF) - tb], 1);
        leidx[pos] = ((unsigned)p) >> 16;
    }
    __syncthreads();
    const int total = cntb + ntgt;
    for (int i = t; i < total; i += 256)
        eidx[gbase + i] = leidx[i];
}

// ------------------------------------------------- standalone gemm (layer 2)
__global__ __launch_bounds__(256) void gemm_mfma_f16(const f16* __restrict__ X,
                                                     const f16* __restrict__ Wt,
                                                     f16* __restrict__ Hh, int N) {
    gemm_body<f16>(X, Wt, Hh, N, blockIdx.x);
}

// ---------------- SpMM: 1 wave/target, quad-edge f16x8 gathers.
// HEAD=0 (layer 1): per-edge dis[r] broadcast loads (table unscaled); stores
//   dc*relu(acc+b1) -> layer-2 table is dis[r]-prescaled FOR FREE.
// HEAD=1 (layer 2): NO dis gather (rows prescaled); OOB tail -> zero row ZR.
template <int HEAD>
__global__ __launch_bounds__(256) void spmm_quad(const f16* __restrict__ G,
                                                 const int* __restrict__ off,
                                                 const int* __restrict__ eidx,
                                                 const float* __restrict__ dis,
                                                 const float* __restrict__ bias,
                                                 const float* __restrict__ Wh,
                                                 const float* __restrict__ bh,
                                                 f16* __restrict__ Oh,
                                                 float* __restrict__ out,
                                                 int N, int ZR) {
    const int c = blockIdx.x * 4 + (threadIdx.x >> 6);
    if (c >= N) return;
    const int lane = threadIdx.x & 63;
    const int q = lane >> 4;           // edge slot within quad
    const int f = (lane & 15) * 8;     // feature base (8 feats/lane)
    const int s = off[c], e = off[c + 1];
    const float dc = dis[c];
    float a0 = 0.f, a1 = 0.f, a2 = 0.f, a3 = 0.f;
    float a4 = 0.f, a5 = 0.f, a6 = 0.f, a7 = 0.f;

    int k = s;
    for (; k + 16 <= e; k += 16) {
        int r[4];
#pragma unroll
        for (int j = 0; j < 4; ++j) r[j] = eidx[k + 4 * j + q];
        f16x8 h[4];
        float w[4];
#pragma unroll
        for (int j = 0; j < 4; ++j) {
            h[j] = *(const f16x8*)&G[(size_t)r[j] * D + f];
            if constexpr (HEAD == 0) w[j] = dis[r[j]];
        }
#pragma unroll
        for (int j = 0; j < 4; ++j) {
            float ww = (HEAD == 0) ? w[j] : 1.f;
            a0 += (float)h[j][0] * ww; a1 += (float)h[j][1] * ww;
            a2 += (float)h[j][2] * ww; a3 += (float)h[j][3] * ww;
            a4 += (float)h[j][4] * ww; a5 += (float)h[j][5] * ww;
            a6 += (float)h[j][6] * ww; a7 += (float)h[j][7] * ww;
        }
    }
    if (k < e) {   // guarded full-depth tail
        int r[4];
        float w[4];
#pragma unroll
        for (int j = 0; j < 4; ++j) {
            int idx = k + 4 * j + q;
            bool ok = idx < e;
            if constexpr (HEAD == 0) {
                int rr = ok ? eidx[idx] : 0;
                r[j] = rr;
                w[j] = ok ? dis[rr] : 0.f;
            } else {
                r[j] = ok ? eidx[idx] : ZR;   // zero row contributes 0
            }
        }
        f16x8 h[4];
#pragma unroll
        for (int j = 0; j < 4; ++j)
            h[j] = *(const f16x8*)&G[(size_t)r[j] * D + f];
#pragma unroll
        for (int j = 0; j < 4; ++j) {
            float ww = (HEAD == 0) ? w[j] : 1.f;
            a0 += (float)h[j][0] * ww; a1 += (float)h[j][1] * ww;
            a2 += (float)h[j][2] * ww; a3 += (float)h[j][3] * ww;
            a4 += (float)h[j][4] * ww; a5 += (float)h[j][5] * ww;
            a6 += (float)h[j][6] * ww; a7 += (float)h[j][7] * ww;
        }
    }
    // combine across the 4 lane groups (edges mod 4)
#pragma unroll
    for (int sft = 16; sft < 64; sft <<= 1) {
        a0 += __shfl_xor(a0, sft); a1 += __shfl_xor(a1, sft);
        a2 += __shfl_xor(a2, sft); a3 += __shfl_xor(a3, sft);
        a4 += __shfl_xor(a4, sft); a5 += __shfl_xor(a5, sft);
        a6 += __shfl_xor(a6, sft); a7 += __shfl_xor(a7, sft);
    }
    const float4 bv0 = *(const float4*)&bias[f];
    const float4 bv1 = *(const float4*)&bias[f + 4];

    if constexpr (HEAD == 0) {
        // acc = sum dis[r]*G[r]; out = relu(dc*acc + b1); store dc*out
        const float r0 = fmaxf(dc * a0 + bv0.x, 0.f), r1 = fmaxf(dc * a1 + bv0.y, 0.f);
        const float r2 = fmaxf(dc * a2 + bv0.z, 0.f), r3 = fmaxf(dc * a3 + bv0.w, 0.f);
        const float r4 = fmaxf(dc * a4 + bv1.x, 0.f), r5 = fmaxf(dc * a5 + bv1.y, 0.f);
        const float r6 = fmaxf(dc * a6 + bv1.z, 0.f), r7 = fmaxf(dc * a7 + bv1.w, 0.f);
        if (q == 0) {                  // store dis[c]-prescaled for layer 2
            f16x8 o;
            o[0] = (f16)(dc * r0); o[1] = (f16)(dc * r1);
            o[2] = (f16)(dc * r2); o[3] = (f16)(dc * r3);
            o[4] = (f16)(dc * r4); o[5] = (f16)(dc * r5);
            o[6] = (f16)(dc * r6); o[7] = (f16)(dc * r7);
            *(f16x8*)&Oh[(size_t)c * D + f] = o;
        }
    } else {
        // rows prescaled by dis[r]; out = relu(dc*acc + b2) -> head
        const float r0 = fmaxf(dc * a0 + bv0.x, 0.f), r1 = fmaxf(dc * a1 + bv0.y, 0.f);
        const float r2 = fmaxf(dc * a2 + bv0.z, 0.f), r3 = fmaxf(dc * a3 + bv0.w, 0.f);
        const float r4 = fmaxf(dc * a4 + bv1.x, 0.f), r5 = fmaxf(dc * a5 + bv1.y, 0.f);
        const float r6 = fmaxf(dc * a6 + bv1.z, 0.f), r7 = fmaxf(dc * a7 + bv1.w, 0.f);
        const float* whp = Wh + f * 3;
        float p0 = r0 * whp[0]  + r1 * whp[3]  + r2 * whp[6]  + r3 * whp[9]
                 + r4 * whp[12] + r5 * whp[15] + r6 * whp[18] + r7 * whp[21];
        float p1 = r0 * whp[1]  + r1 * whp[4]  + r2 * whp[7]  + r3 * whp[10]
                 + r4 * whp[13] + r5 * whp[16] + r6 * whp[19] + r7 * whp[22];
        float p2 = r0 * whp[2]  + r1 * whp[5]  + r2 * whp[8]  + r3 * whp[11]
                 + r4 * whp[14] + r5 * whp[17] + r6 * whp[20] + r7 * whp[23];
#pragma unroll
        for (int sft = 1; sft < 16; sft <<= 1) {
            p0 += __shfl_xor(p0, sft);
            p1 += __shfl_xor(p1, sft);
            p2 += __shfl_xor(p2, sft);
        }
        if (lane == 0) {
            out[(size_t)c * 3 + 0] = p0 + bh[0];
            out[(size_t)c * 3 + 1] = p1 + bh[1];
            out[(size_t)c * 3 + 2] = p2 + bh[2];
        }
    }
}

// ---------------------------------------------------------------------------
extern "C" void kernel_launch(void* const* d_in, const int* in_sizes, int n_in,
                              void* d_out, int out_size, void* d_ws, size_t ws_size,
                              hipStream_t stream) {
    const float* x  = (const float*)d_in[0];
    const int*   ei = (const int*)d_in[1];
    const float* W1 = (const float*)d_in[2];
    const float* b1 = (const float*)d_in[3];
    const float* W2 = (const float*)d_in[4];
    const float* b2 = (const float*)d_in[5];
    const float* Wh = (const float*)d_in[6];
    const float* bh = (const float*)d_in[7];
    float* out = (float*)d_out;

    const int N = in_sizes[0] / D;       // 50000 (< 65536 for packing)
    const int E = in_sizes[1] / 2;       // 800000
    const int Etot = E + N;
    const int* row = ei;
    const int* col = ei + E;
    const int NB = (N + 127) >> NBSH;    // 391 buckets
    const int PB = (E + CHUNK - 1) / CHUNK;   // 196 partition blocks
    const int gblocks = (N + 64 + 63) / 64;   // 783: covers rows 0..N (zero row)
    const int ZR = N;                    // zero-row index for OOB tail slots
    const int sblocks = (N + 3) / 4;     // 12500

    // -------- workspace layout
    char* ws = (char*)d_ws;
    size_t o = 0;
    auto alloc = [&](size_t bytes) -> char* {
        char* p = ws + o;
        o = (o + bytes + 255) & ~(size_t)255;
        return p;
    };
    int*   bcur   = (int*)  alloc((size_t)NB * 4);
    int*   off    = (int*)  alloc((size_t)(N + 1) * 4);
    float* dis    = (float*)alloc((size_t)N * 4);
    int*   bstage = (int*)  alloc((size_t)NB * CAP * 4);   // 6.4 MB packed
    int*   eidx   = (int*)  alloc((size_t)Etot * 4);
    f16*   W1t    = (f16*)  alloc((size_t)128 * 128 * 2);
    f16*   W2t    = (f16*)  alloc((size_t)128 * 128 * 2);
    f16*   Hb0    = (f16*)  alloc((size_t)gblocks * 64 * D * 2);  // ping (+pad)
    f16*   Hb1    = (f16*)  alloc((size_t)gblocks * 64 * D * 2);  // pong (+pad)
    (void)ws_size;

    transpose_w<<<3, 1024, 0, stream>>>(W1, W2, W1t, W2t, bcur, NB);
    gemm1_partition<<<PB + gblocks, 256, 0, stream>>>(x, W1t, Hb0, N,
                                                      row, col, bcur, bstage,
                                                      E, NB, PB);
    bucket_fill2<<<NB, 256, 0, stream>>>(bstage, bcur, off, dis, eidx, N, Etot, NB);
    spmm_quad<0><<<sblocks, 256, 0, stream>>>(Hb0, off, eidx, dis, b1,
                                              nullptr, nullptr, Hb1, nullptr, N, ZR);
    gemm_mfma_f16<<<gblocks, 256, 0, stream>>>(Hb1, W2t, Hb0, N);
    spmm_quad<1><<<sblocks, 256, 0, stream>>>(Hb0, off, eidx, dis, b2,
                                              Wh, bh, nullptr, out, N, ZR);
}